// Round 5
// baseline (145.364 us; speedup 1.0000x reference)
//
#include <hip/hip_runtime.h>

// Loss = mean(0.5*(o-t)^2 * ef(t)) over N = 64*1*512*512 = 2^24 fp32 elements.
// ef(t) = BETA - exp((A-1)*ln(x) - x + BIAS),  x = (t - LOC)/SCALE  (see R0 notes)
// R2/R4: compiler repeatedly collapsed 16-deep load schedules (VGPR=36,
// ~2-4 loads in flight, 44us). R5: ONE monolithic asm block issues all 16
// global_load_dwordx4 (early-clobber outputs -> 64+ VGPRs forced live),
// then staged s_waitcnt vmcnt(14-2r) + opaque-zero guard consumption.

#define NBLOCKS 2048
#define NTHREADS 256
#define F4_PER_THREAD 8   // 2048*256*8*4 = 2^24 elements exactly

__device__ __forceinline__ float ef_term(float o, float y) {
    constexpr float A_M1      = -0.93555708575356741f;  // EST_A - 1
    constexpr float NEG_LOC   =  1.1328205299926424e-27f;
    constexpr float INV_SCALE =  0.65034886603218541f;  // 1/1.5376362609160314
    constexpr float BIAS      = -56.8416699f;
    constexpr float BETA      =  5.0f;

    float x  = (y + NEG_LOC) * INV_SCALE;           // > 0 for y >= 0
    float ex = __expf(fmaf(A_M1, __logf(x), BIAS - x));
    float ef = BETA - ex;                            // == c when y == 0
    float d  = o - y;
    return 0.5f * d * d * ef;
}

// s_waitcnt vmcnt(N), then materialize an opaque 0 in a VGPR. Consumers OR
// their bits with the result -> cannot be hoisted above the wait.
template <int N>
__device__ __forceinline__ unsigned waitcnt_vm_zero() {
    unsigned g;
    asm volatile("s_waitcnt vmcnt(%1)\n\tv_mov_b32 %0, 0"
                 : "=v"(g) : "n"(N) : "memory");
    return g;
}

__device__ __forceinline__ float guard(float v, unsigned g) {
    return __uint_as_float(__float_as_uint(v) | g);
}

__device__ __forceinline__ float block_reduce(float acc) {
    #pragma unroll
    for (int off = 32; off > 0; off >>= 1)
        acc += __shfl_down(acc, off, 64);
    __shared__ float wsum[NTHREADS / 64];
    int lane = threadIdx.x & 63;
    int wave = threadIdx.x >> 6;
    if (lane == 0) wsum[wave] = acc;
    __syncthreads();
    float s = 0.f;
    if (threadIdx.x == 0) {
        #pragma unroll
        for (int w = 0; w < NTHREADS / 64; ++w) s += wsum[w];
    }
    return s;  // valid on thread 0 only
}

// Fast path: n == NBLOCKS*NTHREADS*F4_PER_THREAD*4 exactly.
// Round r is fully coalesced: float4 index = chunk_base + r*NTHREADS + tid.
__global__ __launch_bounds__(NTHREADS, 2) void ef_loss_partial_fast(
    const float* __restrict__ out, const float* __restrict__ tgt,
    float* __restrict__ partials) {
    const int base = blockIdx.x * (NTHREADS * F4_PER_THREAD) + threadIdx.x;
    const float4* __restrict__ op = (const float4*)out;
    const float4* __restrict__ tp = (const float4*)tgt;

    const float4 *po0 = op + base,               *pt0 = tp + base;
    const float4 *po1 = op + base + 1 * NTHREADS, *pt1 = tp + base + 1 * NTHREADS;
    const float4 *po2 = op + base + 2 * NTHREADS, *pt2 = tp + base + 2 * NTHREADS;
    const float4 *po3 = op + base + 3 * NTHREADS, *pt3 = tp + base + 3 * NTHREADS;
    const float4 *po4 = op + base + 4 * NTHREADS, *pt4 = tp + base + 4 * NTHREADS;
    const float4 *po5 = op + base + 5 * NTHREADS, *pt5 = tp + base + 5 * NTHREADS;
    const float4 *po6 = op + base + 6 * NTHREADS, *pt6 = tp + base + 6 * NTHREADS;
    const float4 *po7 = op + base + 7 * NTHREADS, *pt7 = tp + base + 7 * NTHREADS;

    float4 o0, o1, o2, o3, o4v, o5, o6, o7;
    float4 t0, t1, t2, t3, t4v, t5, t6, t7;

    // All 16 loads in ONE volatile asm block: 64 output VGPRs forced live,
    // no wait can be scheduled inside, issue order = (o0,t0,o1,t1,...,o7,t7)
    // so vmcnt(14-2r) ensures rounds 0..r have landed.
    asm volatile(
        "global_load_dwordx4 %0, %16, off\n\t"
        "global_load_dwordx4 %8, %24, off\n\t"
        "global_load_dwordx4 %1, %17, off\n\t"
        "global_load_dwordx4 %9, %25, off\n\t"
        "global_load_dwordx4 %2, %18, off\n\t"
        "global_load_dwordx4 %10, %26, off\n\t"
        "global_load_dwordx4 %3, %19, off\n\t"
        "global_load_dwordx4 %11, %27, off\n\t"
        "global_load_dwordx4 %4, %20, off\n\t"
        "global_load_dwordx4 %12, %28, off\n\t"
        "global_load_dwordx4 %5, %21, off\n\t"
        "global_load_dwordx4 %13, %29, off\n\t"
        "global_load_dwordx4 %6, %22, off\n\t"
        "global_load_dwordx4 %14, %30, off\n\t"
        "global_load_dwordx4 %7, %23, off\n\t"
        "global_load_dwordx4 %15, %31, off"
        : "=&v"(o0), "=&v"(o1), "=&v"(o2), "=&v"(o3),
          "=&v"(o4v), "=&v"(o5), "=&v"(o6), "=&v"(o7),
          "=&v"(t0), "=&v"(t1), "=&v"(t2), "=&v"(t3),
          "=&v"(t4v), "=&v"(t5), "=&v"(t6), "=&v"(t7)
        : "v"(po0), "v"(po1), "v"(po2), "v"(po3),
          "v"(po4), "v"(po5), "v"(po6), "v"(po7),
          "v"(pt0), "v"(pt1), "v"(pt2), "v"(pt3),
          "v"(pt4), "v"(pt5), "v"(pt6), "v"(pt7)
        : "memory");

    float a0 = 0.f, a1 = 0.f, a2 = 0.f, a3 = 0.f;

#define EF_ROUND(r, ov, tv)                                                 \
    do {                                                                    \
        unsigned g = waitcnt_vm_zero<14 - 2 * (r)>();                       \
        a0 += ef_term(guard(ov.x, g), guard(tv.x, g));                      \
        a1 += ef_term(guard(ov.y, g), guard(tv.y, g));                      \
        a2 += ef_term(guard(ov.z, g), guard(tv.z, g));                      \
        a3 += ef_term(guard(ov.w, g), guard(tv.w, g));                      \
    } while (0)

    EF_ROUND(0, o0, t0);
    EF_ROUND(1, o1, t1);
    EF_ROUND(2, o2, t2);
    EF_ROUND(3, o3, t3);
    EF_ROUND(4, o4v, t4v);
    EF_ROUND(5, o5, t5);
    EF_ROUND(6, o6, t6);
    EF_ROUND(7, o7, t7);
#undef EF_ROUND

    float s = block_reduce((a0 + a1) + (a2 + a3));
    if (threadIdx.x == 0) partials[blockIdx.x] = s;
}

// Generic fallback (any n).
__global__ __launch_bounds__(NTHREADS) void ef_loss_partial_gen(
    const float* __restrict__ out, const float* __restrict__ tgt,
    float* __restrict__ partials, int n) {
    const int idx    = blockIdx.x * blockDim.x + threadIdx.x;
    const int stride = gridDim.x * blockDim.x;
    const int n4     = n >> 2;
    const float4* __restrict__ o4 = (const float4*)out;
    const float4* __restrict__ t4 = (const float4*)tgt;

    float acc = 0.f;
    for (int i = idx; i < n4; i += stride) {
        float4 o = o4[i];
        float4 t = t4[i];
        acc += ef_term(o.x, t.x);
        acc += ef_term(o.y, t.y);
        acc += ef_term(o.z, t.z);
        acc += ef_term(o.w, t.w);
    }
    for (int i = (n4 << 2) + idx; i < n; i += stride)
        acc += ef_term(out[i], tgt[i]);

    float s = block_reduce(acc);
    if (threadIdx.x == 0) partials[blockIdx.x] = s;
}

__global__ __launch_bounds__(NTHREADS) void ef_loss_finalize(
    const float* __restrict__ partials, float* __restrict__ result,
    int nblocks, float inv_n) {
    float acc = 0.f;
    for (int i = threadIdx.x; i < nblocks; i += blockDim.x)
        acc += partials[i];
    float s = block_reduce(acc);
    if (threadIdx.x == 0) result[0] = s * inv_n;
}

extern "C" void kernel_launch(void* const* d_in, const int* in_sizes, int n_in,
                              void* d_out, int out_size, void* d_ws, size_t ws_size,
                              hipStream_t stream) {
    const float* out_p = (const float*)d_in[0];   // "output"
    const float* tgt_p = (const float*)d_in[1];   // "target"
    float* partials = (float*)d_ws;               // NBLOCKS floats = 8 KB
    float* result   = (float*)d_out;
    const int n = in_sizes[0];

    if (n == NBLOCKS * NTHREADS * F4_PER_THREAD * 4) {
        ef_loss_partial_fast<<<NBLOCKS, NTHREADS, 0, stream>>>(out_p, tgt_p, partials);
    } else {
        ef_loss_partial_gen<<<NBLOCKS, NTHREADS, 0, stream>>>(out_p, tgt_p, partials, n);
    }
    ef_loss_finalize<<<1, NTHREADS, 0, stream>>>(partials, result, NBLOCKS,
                                                 1.0f / (float)n);
}

// Round 6
// 137.635 us; speedup vs baseline: 1.0561x; 1.0561x over previous
//
#include <hip/hip_runtime.h>

// Loss = mean(0.5*(o-t)^2 * ef(t)) over N = 64*1*512*512 = 2^24 fp32 elements.
// ef(t) = BETA - exp((A-1)*ln(x) - x + BIAS),  x = (t - LOC)/SCALE  (see R0 notes)
// R1-R5: four schedules (2..16 loads in flight, 26..67% occupancy) all pin at
// 44us = 3.0 TB/s demand read (FETCH=65.6MB: half L3-warm, half HBM).
// Service-side cap, not latency. R6 experiment: NON-TEMPORAL loads bypass
// L2/L3 allocation -> both streams symmetric from HBM. Tell: FETCH doubles.

#define NBLOCKS 2048
#define NTHREADS 256
#define F4_PER_THREAD 8   // 2048*256*8*4 = 2^24 elements exactly

typedef __attribute__((ext_vector_type(4))) float f4;

__device__ __forceinline__ float ef_term(float o, float y) {
    constexpr float A_M1      = -0.93555708575356741f;  // EST_A - 1
    constexpr float NEG_LOC   =  1.1328205299926424e-27f;
    constexpr float INV_SCALE =  0.65034886603218541f;  // 1/1.5376362609160314
    constexpr float BIAS      = -56.8416699f;
    constexpr float BETA      =  5.0f;

    float x  = (y + NEG_LOC) * INV_SCALE;           // > 0 for y >= 0
    float ex = __expf(fmaf(A_M1, __logf(x), BIAS - x));
    float ef = BETA - ex;                            // == c when y == 0
    float d  = o - y;
    return 0.5f * d * d * ef;
}

__device__ __forceinline__ float block_reduce(float acc) {
    #pragma unroll
    for (int off = 32; off > 0; off >>= 1)
        acc += __shfl_down(acc, off, 64);
    __shared__ float wsum[NTHREADS / 64];
    int lane = threadIdx.x & 63;
    int wave = threadIdx.x >> 6;
    if (lane == 0) wsum[wave] = acc;
    __syncthreads();
    float s = 0.f;
    if (threadIdx.x == 0) {
        #pragma unroll
        for (int w = 0; w < NTHREADS / 64; ++w) s += wsum[w];
    }
    return s;  // valid on thread 0 only
}

// Fast path: n == NBLOCKS*NTHREADS*F4_PER_THREAD*4 exactly.
// Round r fully coalesced: float4 index = chunk_base + r*NTHREADS + tid.
// All loads non-temporal (bypass L2/L3 allocation).
__global__ __launch_bounds__(NTHREADS) void ef_loss_partial_fast(
    const float* __restrict__ out, const float* __restrict__ tgt,
    float* __restrict__ partials) {
    const int base = blockIdx.x * (NTHREADS * F4_PER_THREAD) + threadIdx.x;
    const f4* __restrict__ o4 = (const f4*)out;
    const f4* __restrict__ t4 = (const f4*)tgt;

    f4 o[F4_PER_THREAD], t[F4_PER_THREAD];
    #pragma unroll
    for (int r = 0; r < F4_PER_THREAD; ++r) {
        o[r] = __builtin_nontemporal_load(o4 + base + r * NTHREADS);
        t[r] = __builtin_nontemporal_load(t4 + base + r * NTHREADS);
    }

    float a0 = 0.f, a1 = 0.f, a2 = 0.f, a3 = 0.f;
    #pragma unroll
    for (int r = 0; r < F4_PER_THREAD; ++r) {
        a0 += ef_term(o[r].x, t[r].x);
        a1 += ef_term(o[r].y, t[r].y);
        a2 += ef_term(o[r].z, t[r].z);
        a3 += ef_term(o[r].w, t[r].w);
    }
    float s = block_reduce((a0 + a1) + (a2 + a3));
    if (threadIdx.x == 0) partials[blockIdx.x] = s;
}

// Generic fallback (any n).
__global__ __launch_bounds__(NTHREADS) void ef_loss_partial_gen(
    const float* __restrict__ out, const float* __restrict__ tgt,
    float* __restrict__ partials, int n) {
    const int idx    = blockIdx.x * blockDim.x + threadIdx.x;
    const int stride = gridDim.x * blockDim.x;
    const int n4     = n >> 2;
    const float4* __restrict__ o4 = (const float4*)out;
    const float4* __restrict__ t4 = (const float4*)tgt;

    float acc = 0.f;
    for (int i = idx; i < n4; i += stride) {
        float4 o = o4[i];
        float4 t = t4[i];
        acc += ef_term(o.x, t.x);
        acc += ef_term(o.y, t.y);
        acc += ef_term(o.z, t.z);
        acc += ef_term(o.w, t.w);
    }
    for (int i = (n4 << 2) + idx; i < n; i += stride)
        acc += ef_term(out[i], tgt[i]);

    float s = block_reduce(acc);
    if (threadIdx.x == 0) partials[blockIdx.x] = s;
}

__global__ __launch_bounds__(NTHREADS) void ef_loss_finalize(
    const float* __restrict__ partials, float* __restrict__ result,
    int nblocks, float inv_n) {
    float acc = 0.f;
    for (int i = threadIdx.x; i < nblocks; i += blockDim.x)
        acc += partials[i];
    float s = block_reduce(acc);
    if (threadIdx.x == 0) result[0] = s * inv_n;
}

extern "C" void kernel_launch(void* const* d_in, const int* in_sizes, int n_in,
                              void* d_out, int out_size, void* d_ws, size_t ws_size,
                              hipStream_t stream) {
    const float* out_p = (const float*)d_in[0];   // "output"
    const float* tgt_p = (const float*)d_in[1];   // "target"
    float* partials = (float*)d_ws;               // NBLOCKS floats = 8 KB
    float* result   = (float*)d_out;
    const int n = in_sizes[0];

    if (n == NBLOCKS * NTHREADS * F4_PER_THREAD * 4) {
        ef_loss_partial_fast<<<NBLOCKS, NTHREADS, 0, stream>>>(out_p, tgt_p, partials);
    } else {
        ef_loss_partial_gen<<<NBLOCKS, NTHREADS, 0, stream>>>(out_p, tgt_p, partials, n);
    }
    ef_loss_finalize<<<1, NTHREADS, 0, stream>>>(partials, result, NBLOCKS,
                                                 1.0f / (float)n);
}

// Round 7
// 132.917 us; speedup vs baseline: 1.0936x; 1.0355x over previous
//
#include <hip/hip_runtime.h>

// Loss = mean(0.5*(o-t)^2 * ef(t)) over N = 64*1*512*512 = 2^24 fp32 elements.
// ef(t) = BETA - exp((A-1)*ln(x) - x + BIAS),  x = (t - LOC)/SCALE  (see R0 notes)
// R1-R5: coherent reads pinned at 3.0 TB/s (cross-XCD probe service wall),
// insensitive to MLP/occupancy. R6: NT both streams -> kernel ~36us (win).
// R7: split paths — `out` NT (pure HBM stream), `tgt` cached/coherent (L3-warm
// from harness restore). Two service paths run concurrently.

#define NBLOCKS 2048
#define NTHREADS 256
#define F4_PER_THREAD 8   // 2048*256*8*4 = 2^24 elements exactly

typedef __attribute__((ext_vector_type(4))) float f4;

__device__ __forceinline__ float ef_term(float o, float y) {
    constexpr float A_M1      = -0.93555708575356741f;  // EST_A - 1
    constexpr float NEG_LOC   =  1.1328205299926424e-27f;
    constexpr float INV_SCALE =  0.65034886603218541f;  // 1/1.5376362609160314
    constexpr float BIAS      = -56.8416699f;
    constexpr float BETA      =  5.0f;

    float x  = (y + NEG_LOC) * INV_SCALE;           // > 0 for y >= 0
    float ex = __expf(fmaf(A_M1, __logf(x), BIAS - x));
    float ef = BETA - ex;                            // == c when y == 0
    float d  = o - y;
    return 0.5f * d * d * ef;
}

__device__ __forceinline__ float block_reduce(float acc) {
    #pragma unroll
    for (int off = 32; off > 0; off >>= 1)
        acc += __shfl_down(acc, off, 64);
    __shared__ float wsum[NTHREADS / 64];
    int lane = threadIdx.x & 63;
    int wave = threadIdx.x >> 6;
    if (lane == 0) wsum[wave] = acc;
    __syncthreads();
    float s = 0.f;
    if (threadIdx.x == 0) {
        #pragma unroll
        for (int w = 0; w < NTHREADS / 64; ++w) s += wsum[w];
    }
    return s;  // valid on thread 0 only
}

// Fast path: n == NBLOCKS*NTHREADS*F4_PER_THREAD*4 exactly.
// Round r fully coalesced: float4 index = chunk_base + r*NTHREADS + tid.
// `out` loads non-temporal (HBM stream); `tgt` loads cached (coherent/L3).
__global__ __launch_bounds__(NTHREADS) void ef_loss_partial_fast(
    const float* __restrict__ out, const float* __restrict__ tgt,
    float* __restrict__ partials) {
    const int base = blockIdx.x * (NTHREADS * F4_PER_THREAD) + threadIdx.x;
    const f4* __restrict__ o4 = (const f4*)out;
    const f4* __restrict__ t4 = (const f4*)tgt;

    f4 o[F4_PER_THREAD], t[F4_PER_THREAD];
    #pragma unroll
    for (int r = 0; r < F4_PER_THREAD; ++r) {
        o[r] = __builtin_nontemporal_load(o4 + base + r * NTHREADS);
        t[r] = t4[base + r * NTHREADS];
    }

    float a0 = 0.f, a1 = 0.f, a2 = 0.f, a3 = 0.f;
    #pragma unroll
    for (int r = 0; r < F4_PER_THREAD; ++r) {
        a0 += ef_term(o[r].x, t[r].x);
        a1 += ef_term(o[r].y, t[r].y);
        a2 += ef_term(o[r].z, t[r].z);
        a3 += ef_term(o[r].w, t[r].w);
    }
    float s = block_reduce((a0 + a1) + (a2 + a3));
    if (threadIdx.x == 0) partials[blockIdx.x] = s;
}

// Generic fallback (any n).
__global__ __launch_bounds__(NTHREADS) void ef_loss_partial_gen(
    const float* __restrict__ out, const float* __restrict__ tgt,
    float* __restrict__ partials, int n) {
    const int idx    = blockIdx.x * blockDim.x + threadIdx.x;
    const int stride = gridDim.x * blockDim.x;
    const int n4     = n >> 2;
    const float4* __restrict__ o4 = (const float4*)out;
    const float4* __restrict__ t4 = (const float4*)tgt;

    float acc = 0.f;
    for (int i = idx; i < n4; i += stride) {
        float4 o = o4[i];
        float4 t = t4[i];
        acc += ef_term(o.x, t.x);
        acc += ef_term(o.y, t.y);
        acc += ef_term(o.z, t.z);
        acc += ef_term(o.w, t.w);
    }
    for (int i = (n4 << 2) + idx; i < n; i += stride)
        acc += ef_term(out[i], tgt[i]);

    float s = block_reduce(acc);
    if (threadIdx.x == 0) partials[blockIdx.x] = s;
}

__global__ __launch_bounds__(NTHREADS) void ef_loss_finalize(
    const float* __restrict__ partials, float* __restrict__ result,
    int nblocks, float inv_n) {
    float acc = 0.f;
    for (int i = threadIdx.x; i < nblocks; i += blockDim.x)
        acc += partials[i];
    float s = block_reduce(acc);
    if (threadIdx.x == 0) result[0] = s * inv_n;
}

extern "C" void kernel_launch(void* const* d_in, const int* in_sizes, int n_in,
                              void* d_out, int out_size, void* d_ws, size_t ws_size,
                              hipStream_t stream) {
    const float* out_p = (const float*)d_in[0];   // "output"
    const float* tgt_p = (const float*)d_in[1];   // "target"
    float* partials = (float*)d_ws;               // NBLOCKS floats = 8 KB
    float* result   = (float*)d_out;
    const int n = in_sizes[0];

    if (n == NBLOCKS * NTHREADS * F4_PER_THREAD * 4) {
        ef_loss_partial_fast<<<NBLOCKS, NTHREADS, 0, stream>>>(out_p, tgt_p, partials);
    } else {
        ef_loss_partial_gen<<<NBLOCKS, NTHREADS, 0, stream>>>(out_p, tgt_p, partials, n);
    }
    ef_loss_finalize<<<1, NTHREADS, 0, stream>>>(partials, result, NBLOCKS,
                                                 1.0f / (float)n);
}

// Round 8
// 132.904 us; speedup vs baseline: 1.0937x; 1.0001x over previous
//
#include <hip/hip_runtime.h>

// Loss = mean(0.5*(o-t)^2 * ef(t)) over N = 64*1*512*512 = 2^24 fp32 elements.
// ef(t) = BETA - exp((A-1)*ln(x) - x + BIAS),  x = (t - LOC)/SCALE  (see R0 notes)
// R1-R5: coherent reads pinned at 3.0 TB/s regardless of MLP/occupancy.
// R6: all-NT -> 3.7 TB/s (kernel ~36us). R7: out=NT, tgt=cached -> 4.3 TB/s
// (~31us) — paths overlap partially. R8: NT path has never run with deep MLP
// (only coherent was asm-pinned, R5). Monolithic 16-deep asm: o-loads `nt`,
// t-loads cached, staged vmcnt(14-2r) consumption.

#define NBLOCKS 2048
#define NTHREADS 256
#define F4_PER_THREAD 8   // 2048*256*8*4 = 2^24 elements exactly

__device__ __forceinline__ float ef_term(float o, float y) {
    constexpr float A_M1      = -0.93555708575356741f;  // EST_A - 1
    constexpr float NEG_LOC   =  1.1328205299926424e-27f;
    constexpr float INV_SCALE =  0.65034886603218541f;  // 1/1.5376362609160314
    constexpr float BIAS      = -56.8416699f;
    constexpr float BETA      =  5.0f;

    float x  = (y + NEG_LOC) * INV_SCALE;           // > 0 for y >= 0
    float ex = __expf(fmaf(A_M1, __logf(x), BIAS - x));
    float ef = BETA - ex;                            // == c when y == 0
    float d  = o - y;
    return 0.5f * d * d * ef;
}

// s_waitcnt vmcnt(N), then materialize an opaque 0 in a VGPR. Consumers OR
// their bits with the result -> cannot be hoisted above the wait.
template <int N>
__device__ __forceinline__ unsigned waitcnt_vm_zero() {
    unsigned g;
    asm volatile("s_waitcnt vmcnt(%1)\n\tv_mov_b32 %0, 0"
                 : "=v"(g) : "n"(N) : "memory");
    return g;
}

__device__ __forceinline__ float guard(float v, unsigned g) {
    return __uint_as_float(__float_as_uint(v) | g);
}

__device__ __forceinline__ float block_reduce(float acc) {
    #pragma unroll
    for (int off = 32; off > 0; off >>= 1)
        acc += __shfl_down(acc, off, 64);
    __shared__ float wsum[NTHREADS / 64];
    int lane = threadIdx.x & 63;
    int wave = threadIdx.x >> 6;
    if (lane == 0) wsum[wave] = acc;
    __syncthreads();
    float s = 0.f;
    if (threadIdx.x == 0) {
        #pragma unroll
        for (int w = 0; w < NTHREADS / 64; ++w) s += wsum[w];
    }
    return s;  // valid on thread 0 only
}

// Fast path: n == NBLOCKS*NTHREADS*F4_PER_THREAD*4 exactly.
// Round r fully coalesced: float4 index = chunk_base + r*NTHREADS + tid.
// 16 loads issued in ONE asm block (order o0,t0,o1,t1,...): o-loads NT
// (HBM stream, bypass L2/L3 alloc), t-loads cached (coherent/L3-warm).
__global__ __launch_bounds__(NTHREADS, 2) void ef_loss_partial_fast(
    const float* __restrict__ out, const float* __restrict__ tgt,
    float* __restrict__ partials) {
    const int base = blockIdx.x * (NTHREADS * F4_PER_THREAD) + threadIdx.x;
    const float4* __restrict__ op = (const float4*)out;
    const float4* __restrict__ tp = (const float4*)tgt;

    const float4 *po0 = op + base,                *pt0 = tp + base;
    const float4 *po1 = op + base + 1 * NTHREADS, *pt1 = tp + base + 1 * NTHREADS;
    const float4 *po2 = op + base + 2 * NTHREADS, *pt2 = tp + base + 2 * NTHREADS;
    const float4 *po3 = op + base + 3 * NTHREADS, *pt3 = tp + base + 3 * NTHREADS;
    const float4 *po4 = op + base + 4 * NTHREADS, *pt4 = tp + base + 4 * NTHREADS;
    const float4 *po5 = op + base + 5 * NTHREADS, *pt5 = tp + base + 5 * NTHREADS;
    const float4 *po6 = op + base + 6 * NTHREADS, *pt6 = tp + base + 6 * NTHREADS;
    const float4 *po7 = op + base + 7 * NTHREADS, *pt7 = tp + base + 7 * NTHREADS;

    float4 o0, o1, o2, o3, o4v, o5, o6, o7;
    float4 t0, t1, t2, t3, t4v, t5, t6, t7;

    asm volatile(
        "global_load_dwordx4 %0, %16, off nt\n\t"
        "global_load_dwordx4 %8, %24, off\n\t"
        "global_load_dwordx4 %1, %17, off nt\n\t"
        "global_load_dwordx4 %9, %25, off\n\t"
        "global_load_dwordx4 %2, %18, off nt\n\t"
        "global_load_dwordx4 %10, %26, off\n\t"
        "global_load_dwordx4 %3, %19, off nt\n\t"
        "global_load_dwordx4 %11, %27, off\n\t"
        "global_load_dwordx4 %4, %20, off nt\n\t"
        "global_load_dwordx4 %12, %28, off\n\t"
        "global_load_dwordx4 %5, %21, off nt\n\t"
        "global_load_dwordx4 %13, %29, off\n\t"
        "global_load_dwordx4 %6, %22, off nt\n\t"
        "global_load_dwordx4 %14, %30, off\n\t"
        "global_load_dwordx4 %7, %23, off nt\n\t"
        "global_load_dwordx4 %15, %31, off"
        : "=&v"(o0), "=&v"(o1), "=&v"(o2), "=&v"(o3),
          "=&v"(o4v), "=&v"(o5), "=&v"(o6), "=&v"(o7),
          "=&v"(t0), "=&v"(t1), "=&v"(t2), "=&v"(t3),
          "=&v"(t4v), "=&v"(t5), "=&v"(t6), "=&v"(t7)
        : "v"(po0), "v"(po1), "v"(po2), "v"(po3),
          "v"(po4), "v"(po5), "v"(po6), "v"(po7),
          "v"(pt0), "v"(pt1), "v"(pt2), "v"(pt3),
          "v"(pt4), "v"(pt5), "v"(pt6), "v"(pt7)
        : "memory");

    float a0 = 0.f, a1 = 0.f, a2 = 0.f, a3 = 0.f;

#define EF_ROUND(r, ov, tv)                                                 \
    do {                                                                    \
        unsigned g = waitcnt_vm_zero<14 - 2 * (r)>();                       \
        a0 += ef_term(guard(ov.x, g), guard(tv.x, g));                      \
        a1 += ef_term(guard(ov.y, g), guard(tv.y, g));                      \
        a2 += ef_term(guard(ov.z, g), guard(tv.z, g));                      \
        a3 += ef_term(guard(ov.w, g), guard(tv.w, g));                      \
    } while (0)

    EF_ROUND(0, o0, t0);
    EF_ROUND(1, o1, t1);
    EF_ROUND(2, o2, t2);
    EF_ROUND(3, o3, t3);
    EF_ROUND(4, o4v, t4v);
    EF_ROUND(5, o5, t5);
    EF_ROUND(6, o6, t6);
    EF_ROUND(7, o7, t7);
#undef EF_ROUND

    float s = block_reduce((a0 + a1) + (a2 + a3));
    if (threadIdx.x == 0) partials[blockIdx.x] = s;
}

// Generic fallback (any n).
__global__ __launch_bounds__(NTHREADS) void ef_loss_partial_gen(
    const float* __restrict__ out, const float* __restrict__ tgt,
    float* __restrict__ partials, int n) {
    const int idx    = blockIdx.x * blockDim.x + threadIdx.x;
    const int stride = gridDim.x * blockDim.x;
    const int n4     = n >> 2;
    const float4* __restrict__ o4 = (const float4*)out;
    const float4* __restrict__ t4 = (const float4*)tgt;

    float acc = 0.f;
    for (int i = idx; i < n4; i += stride) {
        float4 o = o4[i];
        float4 t = t4[i];
        acc += ef_term(o.x, t.x);
        acc += ef_term(o.y, t.y);
        acc += ef_term(o.z, t.z);
        acc += ef_term(o.w, t.w);
    }
    for (int i = (n4 << 2) + idx; i < n; i += stride)
        acc += ef_term(out[i], tgt[i]);

    float s = block_reduce(acc);
    if (threadIdx.x == 0) partials[blockIdx.x] = s;
}

__global__ __launch_bounds__(NTHREADS) void ef_loss_finalize(
    const float* __restrict__ partials, float* __restrict__ result,
    int nblocks, float inv_n) {
    float acc = 0.f;
    for (int i = threadIdx.x; i < nblocks; i += blockDim.x)
        acc += partials[i];
    float s = block_reduce(acc);
    if (threadIdx.x == 0) result[0] = s * inv_n;
}

extern "C" void kernel_launch(void* const* d_in, const int* in_sizes, int n_in,
                              void* d_out, int out_size, void* d_ws, size_t ws_size,
                              hipStream_t stream) {
    const float* out_p = (const float*)d_in[0];   // "output"
    const float* tgt_p = (const float*)d_in[1];   // "target"
    float* partials = (float*)d_ws;               // NBLOCKS floats = 8 KB
    float* result   = (float*)d_out;
    const int n = in_sizes[0];

    if (n == NBLOCKS * NTHREADS * F4_PER_THREAD * 4) {
        ef_loss_partial_fast<<<NBLOCKS, NTHREADS, 0, stream>>>(out_p, tgt_p, partials);
    } else {
        ef_loss_partial_gen<<<NBLOCKS, NTHREADS, 0, stream>>>(out_p, tgt_p, partials, n);
    }
    ef_loss_finalize<<<1, NTHREADS, 0, stream>>>(partials, result, NBLOCKS,
                                                 1.0f / (float)n);
}